// Round 5
// baseline (4392.073 us; speedup 1.0000x reference)
//
#include <hip/hip_runtime.h>

// ---------------------------------------------------------------------------
// MashDecoderV2: 256-layer mamba stack (L=400, D=40) + 65536-query cross-attn
// decoder. f32 throughout (threshold 1.56e-2; current absmax 2e-3).
//
// Stage 1 (round-5): SYSTOLIC 2-LAYER WORKGROUPS. 128 WGs x 640 threads.
//   Waves 0-4 = layer 2w, waves 5-9 = layer 2w+1. Lock-step phase clock via
//   the 5 per-cycle __syncthreads: at cycle p stage 0 does chunk p, stage 1
//   does chunk p-1. Intra-WG handoff = 640B LDS buffer (~0.1us) instead of
//   IF$ (~3.4us) -> IF$ crossings halve: critical path 256C+128F+99C.
//   WG-boundary handoff: serialized flag-poll THEN data loads (per-thread
//   program order guarantees fresh data; R4's speculative accept was racy).
// Stage 2 (round-5): wave-pair query kernel. h = readfirstlane(wave&1) makes
//   all k/v + weight addresses provably wave-uniform (scalar-cache path);
//   merges via LDS columns.
// ---------------------------------------------------------------------------

#define CH 4
#define NCHUNK 100       // 400 / CH
#define TPL 320          // threads per layer-stage
#define TPB1 640         // 2 stages per WG

__global__ void init_flags(int* __restrict__ flags) {
  int i = blockIdx.x * 256 + threadIdx.x;
  if (i < 256 * 16) flags[i] = 0;
}

__global__ __launch_bounds__(TPB1, 3) void mamba_pipe(
    const float* __restrict__ mash,
    const float* __restrict__ g_norm_w,   // (256,40)
    const float* __restrict__ g_in_w,     // (256,160,40)
    const float* __restrict__ g_conv_w,   // (256,80,4)
    const float* __restrict__ g_conv_b,   // (256,80)
    const float* __restrict__ g_xp_w,     // (256,35,80)
    const float* __restrict__ g_dt_w,     // (256,80,3)
    const float* __restrict__ g_dt_b,     // (256,80)
    const float* __restrict__ g_alog,     // (256,80,16)
    const float* __restrict__ g_D,        // (256,80)
    const float* __restrict__ g_out_w,    // (256,40,80)
    float* __restrict__ xb0,
    float* __restrict__ xb1,
    int* __restrict__ flags)
{
  const int w = blockIdx.x;              // WG index: layers {2w, 2w+1}
  const int tid = threadIdx.x;
  const int stage = tid / TPL;           // wave-aligned (320 = 5 waves)
  const int ltid = tid - stage * TPL;
  const int layer = w * 2 + stage;

  // LDS: per-stage activations + inter-stage residual handoff (~17 KB)
  __shared__ float hand[160];            // stage0 -> stage1 residual chunk
  __shared__ float s_xin[2][160];
  __shared__ float s_xz[2][640];
  __shared__ float s_xs[2][320];
  __shared__ float s_dbc[2][144];        // stride 36
  __shared__ float s_yb[2][320];
  __shared__ float s_xhist[2][240];

  // ---------------- per-thread stationary weights (registers) --------------
  const int e_in = ltid % 160;
  const int tA = ltid / 160;
  float w_in_r[40];
  {
    const float4* g = (const float4*)(g_in_w + layer * 6400 + e_in * 40);
    const float4* nw = (const float4*)(g_norm_w + layer * 40);
#pragma unroll
    for (int k = 0; k < 10; ++k) {
      float4 v = g[k];
      float4 n = nw[k];
      w_in_r[4 * k] = v.x * n.x; w_in_r[4 * k + 1] = v.y * n.y;
      w_in_r[4 * k + 2] = v.z * n.z; w_in_r[4 * k + 3] = v.w * n.w;
    }
  }
  const int d_c = ltid % 80;
  const int t_c = ltid / 80;
  float cw[4]; float cb;
  {
    float4 v = *(const float4*)(g_conv_w + layer * 320 + d_c * 4);
    cw[0] = v.x; cw[1] = v.y; cw[2] = v.z; cw[3] = v.w;
    cb = g_conv_b[layer * 80 + d_c];
  }
  const int halfp = ltid & 1;
  const int p_x = ltid >> 1;             // only <140 active for x_proj
  const int t_x = p_x / 35, e_x = p_x % 35;
  float w_xp_r[40];
  if (p_x < 140) {
    const float4* g = (const float4*)(g_xp_w + layer * 2800 + e_x * 80 + halfp * 40);
#pragma unroll
    for (int k = 0; k < 10; ++k) {
      float4 v = g[k];
      w_xp_r[4 * k] = v.x; w_xp_r[4 * k + 1] = v.y;
      w_xp_r[4 * k + 2] = v.z; w_xp_r[4 * k + 3] = v.w;
    }
  }
  const int d_ch = ltid >> 2;
  const int qq = ltid & 3;
  float negA[4], hst[4];
  {
    float4 v = *(const float4*)(g_alog + layer * 1280 + ltid * 4);
    negA[0] = -__expf(v.x); negA[1] = -__expf(v.y);
    negA[2] = -__expf(v.z); negA[3] = -__expf(v.w);
    hst[0] = hst[1] = hst[2] = hst[3] = 0.f;
  }
  const float dtw0 = g_dt_w[layer * 240 + d_ch * 3 + 0];
  const float dtw1 = g_dt_w[layer * 240 + d_ch * 3 + 1];
  const float dtw2 = g_dt_w[layer * 240 + d_ch * 3 + 2];
  const float dtb = g_dt_b[layer * 80 + d_ch];
  const float wD = g_D[layer * 80 + d_ch];
  const int p_o = ltid >> 1;
  const int t_o = p_o / 40, e_o = p_o % 40;
  float w_out_r[40];
  {
    const float4* g = (const float4*)(g_out_w + layer * 3200 + e_o * 80 + halfp * 40);
#pragma unroll
    for (int k = 0; k < 10; ++k) {
      float4 v = g[k];
      w_out_r[4 * k] = v.x; w_out_r[4 * k + 1] = v.y;
      w_out_r[4 * k + 2] = v.z; w_out_r[4 * k + 3] = v.w;
    }
  }

  for (int i = ltid; i < 240; i += TPL) s_xhist[stage][i] = 0.f;
  __syncthreads();

  // WG w-1 stage 1 writes xbuf[(w-1)&1]; WG w stage 1 writes xbuf[w&1].
  const float* src = (w == 0) ? mash : ((w & 1) ? xb0 : xb1);
  float* dst = (w & 1) ? xb1 : xb0;
  int* flag_prev = flags + (w - 1) * 16;
  int* flag_cur = flags + w * 16;

  for (int p = 0; p <= NCHUNK; ++p) {
    const int c = p - stage;               // this stage's chunk this cycle
    const bool act = (c >= 0) && (c < NCHUNK);
    const int t0 = c * CH;

    // ---- Phase A: acquire input + in_proj (rmsnorm folded into weights) ----
    if (act) {
      if (stage == 0) {
        if (w > 0) {
          // poll FIRST; data loads below are program-ordered after the
          // observed flag -> fresh at IF$ (producer drained before flag).
          while (__hip_atomic_load(flag_prev, __ATOMIC_RELAXED,
                                   __HIP_MEMORY_SCOPE_AGENT) <= c)
            __builtin_amdgcn_s_sleep(1);
        }
        float xzv[2];
#pragma unroll
        for (int tt = 0; tt < 2; ++tt) {
          const int t = tA + 2 * tt;
          const float* sp = src + (t0 + t) * 40;
          float x[40];
#pragma unroll
          for (int d = 0; d < 40; ++d)
            x[d] = __hip_atomic_load(sp + d, __ATOMIC_RELAXED,
                                     __HIP_MEMORY_SCOPE_AGENT);
          float ss = 0.f, s = 0.f;
#pragma unroll
          for (int d = 0; d < 40; ++d) { ss += x[d] * x[d]; s += w_in_r[d] * x[d]; }
          xzv[tt] = s * rsqrtf(ss * (1.f / 40.f) + 1e-5f);
        }
        s_xz[0][tA * 160 + e_in] = xzv[0];
        s_xz[0][(tA + 2) * 160 + e_in] = xzv[1];
        if (ltid < 160)
          s_xin[0][ltid] = __hip_atomic_load(src + t0 * 40 + ltid,
                                             __ATOMIC_RELAXED,
                                             __HIP_MEMORY_SCOPE_AGENT);
      } else {
        // input = hand[] (written by stage 0 at end of previous cycle)
        float xzv[2];
#pragma unroll
        for (int tt = 0; tt < 2; ++tt) {
          const int t = tA + 2 * tt;
          const float4* hp = (const float4*)&hand[t * 40];
          float x[40];
#pragma unroll
          for (int k = 0; k < 10; ++k) {
            float4 v = hp[k];
            x[4 * k] = v.x; x[4 * k + 1] = v.y;
            x[4 * k + 2] = v.z; x[4 * k + 3] = v.w;
          }
          float ss = 0.f, s = 0.f;
#pragma unroll
          for (int d = 0; d < 40; ++d) { ss += x[d] * x[d]; s += w_in_r[d] * x[d]; }
          xzv[tt] = s * rsqrtf(ss * (1.f / 40.f) + 1e-5f);
        }
        s_xz[1][tA * 160 + e_in] = xzv[0];
        s_xz[1][(tA + 2) * 160 + e_in] = xzv[1];
        if (ltid < 160) s_xin[1][ltid] = hand[ltid];
      }
    }
    __syncthreads();                                   // B1: xz, xin ready

    // ---- causal depthwise conv(4) + silu ----
    if (act) {
      float acc = cb;
#pragma unroll
      for (int j = 0; j < 4; ++j) {
        int lt = t_c - 3 + j;
        float xv = (lt >= 0) ? s_xz[stage][lt * 160 + d_c]
                             : s_xhist[stage][(lt + 3) * 80 + d_c];
        acc += cw[j] * xv;
      }
      s_xs[stage][t_c * 80 + d_c] = acc / (1.f + __expf(-acc));
    }
    __syncthreads();                                   // B2: xs ready

    // ---- x_proj: pair half-dots + shfl merge; idle threads refresh xhist ----
    if (act) {
      if (p_x < 140) {
        const float4* xp = (const float4*)&s_xs[stage][t_x * 80 + halfp * 40];
        float s = 0.f;
#pragma unroll
        for (int k = 0; k < 10; ++k) {
          float4 v = xp[k];
          s += w_xp_r[4 * k] * v.x + w_xp_r[4 * k + 1] * v.y
             + w_xp_r[4 * k + 2] * v.z + w_xp_r[4 * k + 3] * v.w;
        }
        s += __shfl_xor(s, 1);
        if (halfp == 0) s_dbc[stage][t_x * 36 + e_x] = s;
      } else {
        for (int k = ltid - 280; k < 240; k += 40)
          s_xhist[stage][k] = s_xz[stage][(1 + k / 80) * 160 + (k % 80)];
      }
    }
    __syncthreads();                                   // B3: dbc ready

    // ---- selective scan; dt inline; state in regs ----
    if (act) {
#pragma unroll
      for (int t = 0; t < CH; ++t) {
        const float* db = &s_dbc[stage][t * 36];
        float sdt = dtb + db[0] * dtw0 + db[1] * dtw1 + db[2] * dtw2;
        float dtval = (sdt > 15.f) ? sdt : __logf(1.f + __expf(sdt));
        float xval = s_xs[stage][t * 80 + d_ch];
        float part = 0.f;
#pragma unroll
        for (int j = 0; j < 4; ++j) {
          int s_i = qq * 4 + j;
          float Bv = db[3 + s_i];
          float Cv = db[19 + s_i];
          hst[j] = __expf(dtval * negA[j]) * hst[j] + dtval * Bv * xval;
          part += hst[j] * Cv;
        }
        part += __shfl_xor(part, 1);
        part += __shfl_xor(part, 2);
        if (qq == 0) {
          float yv = part + xval * wD;
          float z = s_xz[stage][t * 160 + 80 + d_ch];
          s_yb[stage][t * 80 + d_ch] = yv * z / (1.f + __expf(-z));
        }
      }
    }
    __syncthreads();                                   // B4: yb ready

    // ---- out_proj + residual: stage0 -> hand (LDS); stage1 -> IF$ ----
    if (act) {
      const float4* yp = (const float4*)&s_yb[stage][t_o * 80 + halfp * 40];
      float s = 0.f;
#pragma unroll
      for (int k = 0; k < 10; ++k) {
        float4 v = yp[k];
        s += w_out_r[4 * k] * v.x + w_out_r[4 * k + 1] * v.y
           + w_out_r[4 * k + 2] * v.z + w_out_r[4 * k + 3] * v.w;
      }
      s += __shfl_xor(s, 1);
      if (halfp == 0) {
        if (stage == 0) hand[p_o] = s_xin[0][p_o] + s;
        else
          __hip_atomic_store(&dst[t0 * 40 + p_o], s_xin[1][p_o] + s,
                             __ATOMIC_RELAXED, __HIP_MEMORY_SCOPE_AGENT);
      }
    }
    __syncthreads();   // B5: drains vmcnt (stage-1 stores acked) + lgkm (hand)
    if (act && stage == 1 && ltid == 0)
      __hip_atomic_store(flag_cur, c + 1, __ATOMIC_RELAXED,
                         __HIP_MEMORY_SCOPE_AGENT);
  }
}

// ---- context side of cross-attn: cn = LN(x_final), kv = cn @ ca_kv_w^T ----
__global__ __launch_bounds__(64) void kv_kernel(
    const float* __restrict__ xfin,
    const float* __restrict__ lnc_w, const float* __restrict__ lnc_b,
    const float* __restrict__ kv_w,
    float* __restrict__ kbuf, float* __restrict__ vbuf)
{
  int t = blockIdx.x;
  int lane = threadIdx.x;
  float x = (lane < 40) ? xfin[t * 40 + lane] : 0.f;
  float s = x;
#pragma unroll
  for (int o = 32; o >= 1; o >>= 1) s += __shfl_xor(s, o);
  float m = s * (1.f / 40.f);
  float dv = (lane < 40) ? (x - m) : 0.f;
  float v2 = dv * dv;
#pragma unroll
  for (int o = 32; o >= 1; o >>= 1) v2 += __shfl_xor(v2, o);
  float rstd = rsqrtf(v2 * (1.f / 40.f) + 1e-5f);
  __shared__ float cn[40];
  if (lane < 40) cn[lane] = dv * rstd * lnc_w[lane] + lnc_b[lane];
  __syncthreads();
  for (int e = lane; e < 80; e += 64) {
    float acc = 0.f;
#pragma unroll
    for (int d = 0; d < 40; ++d) acc += cn[d] * kv_w[e * 40 + d];
    if (e < 40) kbuf[t * 40 + e] = acc;
    else vbuf[t * 40 + (e - 40)] = acc;
  }
}

// ---- per-query decode: wave-pair split; all weight/k/v addresses uniform ----
__global__ __launch_bounds__(256) void query_kernel(
    const float* __restrict__ qry,
    const float* __restrict__ pe_w, const float* __restrict__ pe_b,
    const float* __restrict__ lnq_w, const float* __restrict__ lnq_b,
    const float* __restrict__ qw,
    const float* __restrict__ ow, const float* __restrict__ ob,
    const float* __restrict__ flw, const float* __restrict__ flb,
    const float* __restrict__ w1, const float* __restrict__ b1,
    const float* __restrict__ w2, const float* __restrict__ b2,
    const float* __restrict__ outw, const float* __restrict__ outb,
    const float* __restrict__ kbuf, const float* __restrict__ vbuf,
    float* __restrict__ out)
{
  const int tid = threadIdx.x;
  const int h = __builtin_amdgcn_readfirstlane((tid >> 6) & 1);  // wave in pair
  const int pj = tid >> 7;               // wave-pair 0/1
  const int lane = tid & 63;
  const int n = blockIdx.x * 128 + pj * 64 + lane;   // query id
  const int ptn = tid ^ 64;              // partner thread (other wave in pair)
  __shared__ float colbuf[40 * 256];
  __shared__ float redm[256], redl[256];

  const float qx = qry[n * 3 + 0], qy = qry[n * 3 + 1], qz = qry[n * 3 + 2];

  // ---- PE-MLP, octaves split by wave half ----
  float qp[40];
#pragma unroll
  for (int d = 0; d < 40; ++d) qp[d] = 0.f;
#pragma unroll
  for (int jj = 0; jj < 4; ++jj) {
    const int j = h * 4 + jj;
    float f = 3.14159265358979323846f * (float)(1 << j);
    float sx, cx, sy, cy, sz, cz;
    __sincosf(qx * f, &sx, &cx);
    __sincosf(qy * f, &sy, &cy);
    __sincosf(qz * f, &sz, &cz);
#pragma unroll
    for (int d = 0; d < 40; ++d) {
      const float* r = pe_w + d * 51;
      qp[d] += sx * r[j] + sy * r[j + 8] + sz * r[j + 16]
             + cx * r[j + 24] + cy * r[j + 32] + cz * r[j + 40];
    }
  }
#pragma unroll
  for (int d = 0; d < 40; ++d) colbuf[d * 256 + tid] = qp[d];
  __syncthreads();                                    // B1
  float qe[40];
#pragma unroll
  for (int d = 0; d < 40; ++d) {
    const float* r = pe_w + d * 51;
    qe[d] = pe_b[d] + qp[d] + colbuf[d * 256 + ptn]
          + qx * r[48] + qy * r[49] + qz * r[50];
  }
  __syncthreads();                                    // B2 (colbuf free)

  // ---- LN(qe) -> qn regs; q-proj split by d-half ----
  float qn[40];
  {
    float m = 0.f;
#pragma unroll
    for (int d = 0; d < 40; ++d) m += qe[d];
    m *= (1.f / 40.f);
    float var = 0.f;
#pragma unroll
    for (int d = 0; d < 40; ++d) { float dv = qe[d] - m; var += dv * dv; }
    float rstd = rsqrtf(var * (1.f / 40.f) + 1e-5f);
#pragma unroll
    for (int d = 0; d < 40; ++d) qn[d] = (qe[d] - m) * rstd * lnq_w[d] + lnq_b[d];
  }
  float qnh[20];
#pragma unroll
  for (int dd = 0; dd < 20; ++dd) qnh[dd] = h ? qn[dd + 20] : qn[dd];
  float q[40];
#pragma unroll
  for (int e = 0; e < 40; ++e) q[e] = 0.f;
#pragma unroll 1
  for (int dd = 0; dd < 20; ++dd) {
    const float qv = qnh[dd];
    const int d = h * 20 + dd;
#pragma unroll
    for (int e = 0; e < 40; ++e) q[e] += qv * qw[e * 40 + d];
  }
#pragma unroll
  for (int e = 0; e < 40; ++e) colbuf[e * 256 + tid] = q[e];
  __syncthreads();                                    // B3
#pragma unroll
  for (int e = 0; e < 40; ++e) q[e] += colbuf[e * 256 + ptn];
  __syncthreads();                                    // B4 (colbuf free)

  // ---- flash attention over this wave's 200 tokens (uniform addresses) ----
  float acc[40];
#pragma unroll
  for (int d = 0; d < 40; ++d) acc[d] = 0.f;
  float mx = -1e30f, l = 0.f;
  const float scale = 0.15811388300841897f;  // 40^-0.5
  const int tbeg = h * 200, tend = tbeg + 200;
#pragma unroll 1
  for (int t = tbeg; t < tend; ++t) {
    const float4* kr = (const float4*)(kbuf + t * 40);
    float s0 = 0.f, s1 = 0.f, s2 = 0.f, s3 = 0.f;
#pragma unroll
    for (int k = 0; k < 10; ++k) {
      float4 k4 = kr[k];
      s0 += q[4 * k] * k4.x; s1 += q[4 * k + 1] * k4.y;
      s2 += q[4 * k + 2] * k4.z; s3 += q[4 * k + 3] * k4.w;
    }
    float s = ((s0 + s1) + (s2 + s3)) * scale;
    if (s > mx) {
      float corr = __expf(mx - s);
      l *= corr;
#pragma unroll
      for (int d = 0; d < 40; ++d) acc[d] *= corr;
      mx = s;
    }
    float p = __expf(s - mx);
    l += p;
    const float4* vr = (const float4*)(vbuf + t * 40);
#pragma unroll
    for (int k = 0; k < 10; ++k) {
      float4 v4 = vr[k];
      acc[4 * k] += p * v4.x; acc[4 * k + 1] += p * v4.y;
      acc[4 * k + 2] += p * v4.z; acc[4 * k + 3] += p * v4.w;
    }
  }
  // merge across the wave pair via LDS (symmetric)
#pragma unroll
  for (int d = 0; d < 40; ++d) colbuf[d * 256 + tid] = acc[d];
  redm[tid] = mx; redl[tid] = l;
  __syncthreads();                                    // B5
  float lat[40];
  {
    float m2 = redm[ptn];
    float l2 = redl[ptn];
    float nm = fmaxf(mx, m2);
    float a = __expf(mx - nm), b = __expf(m2 - nm);
    float lm = l * a + l2 * b;
    float linv = 1.f / lm;
#pragma unroll
    for (int d = 0; d < 40; ++d)
      lat[d] = (acc[d] * a + colbuf[d * 256 + ptn] * b) * linv;
  }
  __syncthreads();                                    // B6 (colbuf free)

  // ---- lat2 = lat @ ca_out_w^T + ob, split by d-half ----
  float lath[20];
#pragma unroll
  for (int dd = 0; dd < 20; ++dd) lath[dd] = h ? lat[dd + 20] : lat[dd];
  float lp[40];
#pragma unroll
  for (int e = 0; e < 40; ++e) lp[e] = 0.f;
#pragma unroll 1
  for (int dd = 0; dd < 20; ++dd) {
    const float lv = lath[dd];
    const int d = h * 20 + dd;
#pragma unroll
    for (int e = 0; e < 40; ++e) lp[e] += lv * ow[e * 40 + d];
  }
#pragma unroll
  for (int e = 0; e < 40; ++e) colbuf[e * 256 + tid] = lp[e];
  __syncthreads();                                    // B7
  float lat2[40];
#pragma unroll
  for (int e = 0; e < 40; ++e) lat2[e] = ob[e] + lp[e] + colbuf[e * 256 + ptn];
  __syncthreads();                                    // B8 (colbuf free)

  // ---- LN + FFN (e-range split by wave half) ----
  float hh[40];
  {
    float m = 0.f;
#pragma unroll
    for (int d = 0; d < 40; ++d) m += lat2[d];
    m *= (1.f / 40.f);
    float var = 0.f;
#pragma unroll
    for (int d = 0; d < 40; ++d) { float dv = lat2[d] - m; var += dv * dv; }
    float rstd = rsqrtf(var * (1.f / 40.f) + 1e-5f);
#pragma unroll
    for (int d = 0; d < 40; ++d) hh[d] = (lat2[d] - m) * rstd * flw[d] + flb[d];
  }
  float ff[40];
#pragma unroll
  for (int d = 0; d < 40; ++d) ff[d] = 0.f;
#pragma unroll 1
  for (int ee = 0; ee < 80; ++ee) {
    const int e = h * 80 + ee;
    const float* r1 = w1 + e * 40;
    const float* r2 = w1 + (160 + e) * 40;
    float a0 = 0.f, a1 = 0.f;
#pragma unroll
    for (int d = 0; d < 40; ++d) { a0 += hh[d] * r1[d]; a1 += hh[d] * r2[d]; }
    float x1 = a0 + b1[e];
    float g = a1 + b1[160 + e];
    float tv = x1 * (0.5f * g * (1.f + erff(g * 0.70710678118654752f)));
#pragma unroll
    for (int d = 0; d < 40; ++d) ff[d] += tv * w2[d * 160 + e];
  }
#pragma unroll
  for (int d = 0; d < 40; ++d) colbuf[d * 256 + tid] = ff[d];
  __syncthreads();                                    // B9
  float r = outb[0];
#pragma unroll
  for (int d = 0; d < 40; ++d) {
    float f = ff[d] + colbuf[d * 256 + ptn] + b2[d];
    r += (lat2[d] + f) * outw[d];
  }
  if (h == 0) out[n] = r;
}

extern "C" void kernel_launch(void* const* d_in, const int* in_sizes, int n_in,
                              void* d_out, int out_size, void* d_ws, size_t ws_size,
                              hipStream_t stream) {
  const float* mash   = (const float*)d_in[0];
  const float* qry    = (const float*)d_in[1];
  const float* lnw    = (const float*)d_in[2];
  const float* linw   = (const float*)d_in[3];
  const float* lconvw = (const float*)d_in[4];
  const float* lconvb = (const float*)d_in[5];
  const float* lxpw   = (const float*)d_in[6];
  const float* ldtw   = (const float*)d_in[7];
  const float* ldtb   = (const float*)d_in[8];
  const float* lAlog  = (const float*)d_in[9];
  const float* lD     = (const float*)d_in[10];
  const float* loutw  = (const float*)d_in[11];
  const float* pew    = (const float*)d_in[12];
  const float* peb    = (const float*)d_in[13];
  const float* lnqw   = (const float*)d_in[14];
  const float* lnqb   = (const float*)d_in[15];
  const float* lncw   = (const float*)d_in[16];
  const float* lncb   = (const float*)d_in[17];
  const float* qw     = (const float*)d_in[18];
  const float* kvw    = (const float*)d_in[19];
  const float* oww    = (const float*)d_in[20];
  const float* owb    = (const float*)d_in[21];
  const float* flnw   = (const float*)d_in[22];
  const float* flnb   = (const float*)d_in[23];
  const float* w1     = (const float*)d_in[24];
  const float* b1     = (const float*)d_in[25];
  const float* w2     = (const float*)d_in[26];
  const float* b2     = (const float*)d_in[27];
  const float* outw   = (const float*)d_in[28];
  const float* outb   = (const float*)d_in[29];

  // ws layout (f32 elements): xb0[16000] xb1[16000] k[16000] v[16000] flags
  float* wsf = (float*)d_ws;
  float* xb0 = wsf;
  float* xb1 = wsf + 16000;
  float* kbuf = wsf + 32000;
  float* vbuf = wsf + 48000;
  int* flags = (int*)(wsf + 64000);

  hipLaunchKernelGGL(init_flags, dim3(16), dim3(256), 0, stream, flags);
  hipLaunchKernelGGL(mamba_pipe, dim3(128), dim3(TPB1), 0, stream,
                     mash, lnw, linw, lconvw, lconvb, lxpw, ldtw, ldtb, lAlog,
                     lD, loutw, xb0, xb1, flags);
  // WG 127 (odd) stage 1 writes xb1
  hipLaunchKernelGGL(kv_kernel, dim3(400), dim3(64), 0, stream,
                     xb1, lncw, lncb, kvw, kbuf, vbuf);
  hipLaunchKernelGGL(query_kernel, dim3(512), dim3(256), 0, stream,
                     qry, pew, peb, lnqw, lnqb, qw, oww, owb, flnw, flnb,
                     w1, b1, w2, b2, outw, outb, kbuf, vbuf, (float*)d_out);
}

// Round 6
// 3290.282 us; speedup vs baseline: 1.3349x; 1.3349x over previous
//
#include <hip/hip_runtime.h>

// ---------------------------------------------------------------------------
// MashDecoderV2: 256-layer mamba stack (L=400, D=40) + 65536-query cross-attn
// decoder. f32 throughout (threshold 1.56e-2; current absmax 2e-3).
//
// Stage 1 (round-6): TWO LAYERS SEQUENTIAL PER WG. 128 WGs x 320 threads.
//   Cycle c: layer 2w computes chunk c -> LDS hand[] -> layer 2w+1 computes
//   chunk c -> IF$ store + flag. One IF$ crossing per 2 layers (R4 paid one
//   per layer); same single-barrier-clock 320-thread phase structure as the
//   measured-good R4 (R5's 2-stage 10-wave systolic WG regressed 2.3x and is
//   abandoned). Handoff protocol: relaxed agent-scope atomics, ordered
//   poll -> data loads (per-thread program order; no speculative accept).
// Stage 2: round-5 wave-pair query kernel (measured ~2x faster than R4's):
//   h = readfirstlane(wave&1) -> all weight/k/v addresses wave-uniform.
// ---------------------------------------------------------------------------

#define CH 4
#define NCHUNK 100       // 400 / CH
#define TPB1 320

__global__ void init_flags(int* __restrict__ flags) {
  int i = blockIdx.x * 256 + threadIdx.x;
  if (i < 256 * 16) flags[i] = 0;
}

__global__ __launch_bounds__(TPB1) void mamba_pipe(
    const float* __restrict__ mash,
    const float* __restrict__ g_norm_w,   // (256,40)
    const float* __restrict__ g_in_w,     // (256,160,40)
    const float* __restrict__ g_conv_w,   // (256,80,4)
    const float* __restrict__ g_conv_b,   // (256,80)
    const float* __restrict__ g_xp_w,     // (256,35,80)
    const float* __restrict__ g_dt_w,     // (256,80,3)
    const float* __restrict__ g_dt_b,     // (256,80)
    const float* __restrict__ g_alog,     // (256,80,16)
    const float* __restrict__ g_D,        // (256,80)
    const float* __restrict__ g_out_w,    // (256,40,80)
    float* __restrict__ xb0,
    float* __restrict__ xb1,
    int* __restrict__ flags)
{
  const int w = blockIdx.x;              // this WG owns layers {2w, 2w+1}
  const int tid = threadIdx.x;

  // activations in LDS (~9 KB); xz/xs/dbc/yb reused by both layers
  __shared__ float hand[160];            // layer0 -> layer1 residual chunk
  __shared__ float s_xin[160];           // layer0 residual input copy
  __shared__ float s_xz[640];
  __shared__ float s_xs[320];
  __shared__ float s_dbc[144];           // stride 36
  __shared__ float s_yb[320];
  __shared__ float s_xhist[2][240];      // conv tails, one per layer

  // thread roles (identical for both layers)
  const int e_in = tid % 160;
  const int tA = tid / 160;
  const int d_c = tid % 80;
  const int t_c = tid / 80;
  const int halfp = tid & 1;
  const int p_x = tid >> 1;              // x_proj pair id (<140 active)
  const int t_x = p_x / 35, e_x = p_x % 35;
  const int d_ch = tid >> 2;
  const int qq = tid & 3;
  const int p_o = tid >> 1;              // out_proj pair id
  const int t_o = p_o / 40, e_o = p_o % 40;

  // persistent small per-layer params (registers; L index unrolled-constant)
  float negA[2][4], hst[2][4], cwv[2][4];
  float cbv[2], dtw0[2], dtw1[2], dtw2[2], dtbv[2], wDv[2];
  const float4* win_p[2];
  const float4* nrm_p[2];
  const float4* wxp_p[2];
  const float4* wout_p[2];
#pragma unroll
  for (int L = 0; L < 2; ++L) {
    const int layer = 2 * w + L;
    float4 v = *(const float4*)(g_alog + layer * 1280 + tid * 4);
    negA[L][0] = -__expf(v.x); negA[L][1] = -__expf(v.y);
    negA[L][2] = -__expf(v.z); negA[L][3] = -__expf(v.w);
    hst[L][0] = hst[L][1] = hst[L][2] = hst[L][3] = 0.f;
    float4 cv = *(const float4*)(g_conv_w + layer * 320 + d_c * 4);
    cwv[L][0] = cv.x; cwv[L][1] = cv.y; cwv[L][2] = cv.z; cwv[L][3] = cv.w;
    cbv[L] = g_conv_b[layer * 80 + d_c];
    dtw0[L] = g_dt_w[layer * 240 + d_ch * 3 + 0];
    dtw1[L] = g_dt_w[layer * 240 + d_ch * 3 + 1];
    dtw2[L] = g_dt_w[layer * 240 + d_ch * 3 + 2];
    dtbv[L] = g_dt_b[layer * 80 + d_ch];
    wDv[L] = g_D[layer * 80 + d_ch];
    win_p[L] = (const float4*)(g_in_w + layer * 6400 + e_in * 40);
    nrm_p[L] = (const float4*)(g_norm_w + layer * 40);
    wxp_p[L] = (const float4*)(g_xp_w + layer * 2800 + e_x * 80 + halfp * 40);
    wout_p[L] = (const float4*)(g_out_w + layer * 3200 + e_o * 80 + halfp * 40);
  }
  for (int i = tid; i < 480; i += TPB1) s_xhist[i / 240][i % 240] = 0.f;
  __syncthreads();

  // WG w-1 writes xb[(w-1)&1]; WG w writes xb[w&1]
  const float* src = (w == 0) ? mash : ((w & 1) ? xb0 : xb1);
  float* dst = (w & 1) ? xb1 : xb0;
  int* flag_prev = flags + (w - 1) * 16;
  int* flag_cur = flags + w * 16;

  for (int c = 0; c < NCHUNK; ++c) {
    const int t0 = c * CH;

#pragma unroll
    for (int L = 0; L < 2; ++L) {
      // ---- Phase A: acquire input + in_proj (rmsnorm folded) ----
      {
        // fold norm into this layer's in_proj row (L1/L2-hot reloads)
        float wr[40];
#pragma unroll
        for (int k = 0; k < 10; ++k) {
          float4 a = win_p[L][k];
          float4 n = nrm_p[L][k];
          wr[4 * k] = a.x * n.x; wr[4 * k + 1] = a.y * n.y;
          wr[4 * k + 2] = a.z * n.z; wr[4 * k + 3] = a.w * n.w;
        }
        if (L == 0) {
          if (w > 0) {
            // ordered protocol: observe flag, THEN load (program order)
            while (__hip_atomic_load(flag_prev, __ATOMIC_RELAXED,
                                     __HIP_MEMORY_SCOPE_AGENT) <= c)
              __builtin_amdgcn_s_sleep(1);
#pragma unroll
            for (int tt = 0; tt < 2; ++tt) {
              const int t = tA + 2 * tt;
              const float* sp = src + (t0 + t) * 40;
              float x[40];
#pragma unroll
              for (int d = 0; d < 40; ++d)
                x[d] = __hip_atomic_load(sp + d, __ATOMIC_RELAXED,
                                         __HIP_MEMORY_SCOPE_AGENT);
              float ss = 0.f, s = 0.f;
#pragma unroll
              for (int d = 0; d < 40; ++d) { ss += x[d] * x[d]; s += wr[d] * x[d]; }
              s_xz[t * 160 + e_in] = s * rsqrtf(ss * (1.f / 40.f) + 1e-5f);
            }
            if (tid < 160)
              s_xin[tid] = __hip_atomic_load(src + t0 * 40 + tid,
                                             __ATOMIC_RELAXED,
                                             __HIP_MEMORY_SCOPE_AGENT);
          } else {
            // layer 0 reads the pristine kernel input: plain float4 loads
#pragma unroll
            for (int tt = 0; tt < 2; ++tt) {
              const int t = tA + 2 * tt;
              const float4* sp = (const float4*)(src + (t0 + t) * 40);
              float ss = 0.f, s = 0.f;
#pragma unroll
              for (int k = 0; k < 10; ++k) {
                float4 v = sp[k];
                ss += v.x * v.x + v.y * v.y + v.z * v.z + v.w * v.w;
                s += wr[4 * k] * v.x + wr[4 * k + 1] * v.y
                   + wr[4 * k + 2] * v.z + wr[4 * k + 3] * v.w;
              }
              s_xz[t * 160 + e_in] = s * rsqrtf(ss * (1.f / 40.f) + 1e-5f);
            }
            if (tid < 160) s_xin[tid] = src[t0 * 40 + tid];
          }
        } else {
          // layer 2w+1 input = hand[] (LDS, broadcast reads)
#pragma unroll
          for (int tt = 0; tt < 2; ++tt) {
            const int t = tA + 2 * tt;
            const float4* hp = (const float4*)&hand[t * 40];
            float ss = 0.f, s = 0.f;
#pragma unroll
            for (int k = 0; k < 10; ++k) {
              float4 v = hp[k];
              ss += v.x * v.x + v.y * v.y + v.z * v.z + v.w * v.w;
              s += wr[4 * k] * v.x + wr[4 * k + 1] * v.y
                 + wr[4 * k + 2] * v.z + wr[4 * k + 3] * v.w;
            }
            s_xz[t * 160 + e_in] = s * rsqrtf(ss * (1.f / 40.f) + 1e-5f);
          }
        }
      }
      __syncthreads();                              // xz (+xin) ready

      // ---- causal depthwise conv(4) + silu ----
      {
        float acc = cbv[L];
#pragma unroll
        for (int j = 0; j < 4; ++j) {
          int lt = t_c - 3 + j;
          float xv = (lt >= 0) ? s_xz[lt * 160 + d_c]
                               : s_xhist[L][(lt + 3) * 80 + d_c];
          acc += cwv[L][j] * xv;
        }
        s_xs[t_c * 80 + d_c] = acc / (1.f + __expf(-acc));
      }
      __syncthreads();                              // xs ready

      // ---- x_proj: pair half-dots + shfl merge; idle 40 update xhist ----
      if (p_x < 140) {
        float wr[40];
#pragma unroll
        for (int k = 0; k < 10; ++k) {
          float4 v = wxp_p[L][k];
          wr[4 * k] = v.x; wr[4 * k + 1] = v.y;
          wr[4 * k + 2] = v.z; wr[4 * k + 3] = v.w;
        }
        const float4* xp = (const float4*)&s_xs[t_x * 80 + halfp * 40];
        float s = 0.f;
#pragma unroll
        for (int k = 0; k < 10; ++k) {
          float4 v = xp[k];
          s += wr[4 * k] * v.x + wr[4 * k + 1] * v.y
             + wr[4 * k + 2] * v.z + wr[4 * k + 3] * v.w;
        }
        s += __shfl_xor(s, 1);
        if (halfp == 0) s_dbc[t_x * 36 + e_x] = s;
      } else {
        for (int k = tid - 280; k < 240; k += 40)
          s_xhist[L][k] = s_xz[(1 + k / 80) * 160 + (k % 80)];
      }
      __syncthreads();                              // dbc ready

      // ---- selective scan; dt inline; state in regs ----
#pragma unroll
      for (int t = 0; t < CH; ++t) {
        const float* db = &s_dbc[t * 36];
        float sdt = dtbv[L] + db[0] * dtw0[L] + db[1] * dtw1[L]
                            + db[2] * dtw2[L];
        float dtval = (sdt > 15.f) ? sdt : __logf(1.f + __expf(sdt));
        float xval = s_xs[t * 80 + d_ch];
        float part = 0.f;
#pragma unroll
        for (int j = 0; j < 4; ++j) {
          int s_i = qq * 4 + j;
          float Bv = db[3 + s_i];
          float Cv = db[19 + s_i];
          hst[L][j] = __expf(dtval * negA[L][j]) * hst[L][j] + dtval * Bv * xval;
          part += hst[L][j] * Cv;
        }
        part += __shfl_xor(part, 1);
        part += __shfl_xor(part, 2);
        if (qq == 0) {
          float yv = part + xval * wDv[L];
          float z = s_xz[t * 160 + 80 + d_ch];
          s_yb[t * 80 + d_ch] = yv * z / (1.f + __expf(-z));
        }
      }
      __syncthreads();                              // yb ready

      // ---- out_proj + residual: L0 -> hand (LDS); L1 -> IF$ store ----
      {
        float wr[40];
#pragma unroll
        for (int k = 0; k < 10; ++k) {
          float4 v = wout_p[L][k];
          wr[4 * k] = v.x; wr[4 * k + 1] = v.y;
          wr[4 * k + 2] = v.z; wr[4 * k + 3] = v.w;
        }
        const float4* yp = (const float4*)&s_yb[t_o * 80 + halfp * 40];
        float s = 0.f;
#pragma unroll
        for (int k = 0; k < 10; ++k) {
          float4 v = yp[k];
          s += wr[4 * k] * v.x + wr[4 * k + 1] * v.y
             + wr[4 * k + 2] * v.z + wr[4 * k + 3] * v.w;
        }
        s += __shfl_xor(s, 1);
        if (halfp == 0) {
          if (L == 0) hand[p_o] = s_xin[p_o] + s;
          else
            __hip_atomic_store(&dst[t0 * 40 + p_o], hand[p_o] + s,
                               __ATOMIC_RELAXED, __HIP_MEMORY_SCOPE_AGENT);
        }
      }
      __syncthreads();   // L0: hand ready; L1: drains vmcnt (stores at IF$)
    }
    if (tid == 0)
      __hip_atomic_store(flag_cur, c + 1, __ATOMIC_RELAXED,
                         __HIP_MEMORY_SCOPE_AGENT);
  }
}

// ---- context side of cross-attn: cn = LN(x_final), kv = cn @ ca_kv_w^T ----
__global__ __launch_bounds__(64) void kv_kernel(
    const float* __restrict__ xfin,
    const float* __restrict__ lnc_w, const float* __restrict__ lnc_b,
    const float* __restrict__ kv_w,
    float* __restrict__ kbuf, float* __restrict__ vbuf)
{
  int t = blockIdx.x;
  int lane = threadIdx.x;
  float x = (lane < 40) ? xfin[t * 40 + lane] : 0.f;
  float s = x;
#pragma unroll
  for (int o = 32; o >= 1; o >>= 1) s += __shfl_xor(s, o);
  float m = s * (1.f / 40.f);
  float dv = (lane < 40) ? (x - m) : 0.f;
  float v2 = dv * dv;
#pragma unroll
  for (int o = 32; o >= 1; o >>= 1) v2 += __shfl_xor(v2, o);
  float rstd = rsqrtf(v2 * (1.f / 40.f) + 1e-5f);
  __shared__ float cn[40];
  if (lane < 40) cn[lane] = dv * rstd * lnc_w[lane] + lnc_b[lane];
  __syncthreads();
  for (int e = lane; e < 80; e += 64) {
    float acc = 0.f;
#pragma unroll
    for (int d = 0; d < 40; ++d) acc += cn[d] * kv_w[e * 40 + d];
    if (e < 40) kbuf[t * 40 + e] = acc;
    else vbuf[t * 40 + (e - 40)] = acc;
  }
}

// ---- per-query decode: wave-pair split; all weight/k/v addresses uniform ----
__global__ __launch_bounds__(256) void query_kernel(
    const float* __restrict__ qry,
    const float* __restrict__ pe_w, const float* __restrict__ pe_b,
    const float* __restrict__ lnq_w, const float* __restrict__ lnq_b,
    const float* __restrict__ qw,
    const float* __restrict__ ow, const float* __restrict__ ob,
    const float* __restrict__ flw, const float* __restrict__ flb,
    const float* __restrict__ w1, const float* __restrict__ b1,
    const float* __restrict__ w2, const float* __restrict__ b2,
    const float* __restrict__ outw, const float* __restrict__ outb,
    const float* __restrict__ kbuf, const float* __restrict__ vbuf,
    float* __restrict__ out)
{
  const int tid = threadIdx.x;
  const int h = __builtin_amdgcn_readfirstlane((tid >> 6) & 1);  // wave in pair
  const int pj = tid >> 7;               // wave-pair 0/1
  const int lane = tid & 63;
  const int n = blockIdx.x * 128 + pj * 64 + lane;   // query id
  const int ptn = tid ^ 64;              // partner thread (other wave in pair)
  __shared__ float colbuf[40 * 256];
  __shared__ float redm[256], redl[256];

  const float qx = qry[n * 3 + 0], qy = qry[n * 3 + 1], qz = qry[n * 3 + 2];

  // ---- PE-MLP, octaves split by wave half ----
  float qp[40];
#pragma unroll
  for (int d = 0; d < 40; ++d) qp[d] = 0.f;
#pragma unroll
  for (int jj = 0; jj < 4; ++jj) {
    const int j = h * 4 + jj;
    float f = 3.14159265358979323846f * (float)(1 << j);
    float sx, cx, sy, cy, sz, cz;
    __sincosf(qx * f, &sx, &cx);
    __sincosf(qy * f, &sy, &cy);
    __sincosf(qz * f, &sz, &cz);
#pragma unroll
    for (int d = 0; d < 40; ++d) {
      const float* r = pe_w + d * 51;
      qp[d] += sx * r[j] + sy * r[j + 8] + sz * r[j + 16]
             + cx * r[j + 24] + cy * r[j + 32] + cz * r[j + 40];
    }
  }
#pragma unroll
  for (int d = 0; d < 40; ++d) colbuf[d * 256 + tid] = qp[d];
  __syncthreads();                                    // B1
  float qe[40];
#pragma unroll
  for (int d = 0; d < 40; ++d) {
    const float* r = pe_w + d * 51;
    qe[d] = pe_b[d] + qp[d] + colbuf[d * 256 + ptn]
          + qx * r[48] + qy * r[49] + qz * r[50];
  }
  __syncthreads();                                    // B2 (colbuf free)

  // ---- LN(qe) -> qn regs; q-proj split by d-half ----
  float qn[40];
  {
    float m = 0.f;
#pragma unroll
    for (int d = 0; d < 40; ++d) m += qe[d];
    m *= (1.f / 40.f);
    float var = 0.f;
#pragma unroll
    for (int d = 0; d < 40; ++d) { float dv = qe[d] - m; var += dv * dv; }
    float rstd = rsqrtf(var * (1.f / 40.f) + 1e-5f);
#pragma unroll
    for (int d = 0; d < 40; ++d) qn[d] = (qe[d] - m) * rstd * lnq_w[d] + lnq_b[d];
  }
  float qnh[20];
#pragma unroll
  for (int dd = 0; dd < 20; ++dd) qnh[dd] = h ? qn[dd + 20] : qn[dd];
  float q[40];
#pragma unroll
  for (int e = 0; e < 40; ++e) q[e] = 0.f;
#pragma unroll 1
  for (int dd = 0; dd < 20; ++dd) {
    const float qv = qnh[dd];
    const int d = h * 20 + dd;
#pragma unroll
    for (int e = 0; e < 40; ++e) q[e] += qv * qw[e * 40 + d];
  }
#pragma unroll
  for (int e = 0; e < 40; ++e) colbuf[e * 256 + tid] = q[e];
  __syncthreads();                                    // B3
#pragma unroll
  for (int e = 0; e < 40; ++e) q[e] += colbuf[e * 256 + ptn];
  __syncthreads();                                    // B4 (colbuf free)

  // ---- flash attention over this wave's 200 tokens (uniform addresses) ----
  float acc[40];
#pragma unroll
  for (int d = 0; d < 40; ++d) acc[d] = 0.f;
  float mx = -1e30f, l = 0.f;
  const float scale = 0.15811388300841897f;  // 40^-0.5
  const int tbeg = h * 200, tend = tbeg + 200;
#pragma unroll 1
  for (int t = tbeg; t < tend; ++t) {
    const float4* kr = (const float4*)(kbuf + t * 40);
    float s0 = 0.f, s1 = 0.f, s2 = 0.f, s3 = 0.f;
#pragma unroll
    for (int k = 0; k < 10; ++k) {
      float4 k4 = kr[k];
      s0 += q[4 * k] * k4.x; s1 += q[4 * k + 1] * k4.y;
      s2 += q[4 * k + 2] * k4.z; s3 += q[4 * k + 3] * k4.w;
    }
    float s = ((s0 + s1) + (s2 + s3)) * scale;
    if (s > mx) {
      float corr = __expf(mx - s);
      l *= corr;
#pragma unroll
      for (int d = 0; d < 40; ++d) acc[d] *= corr;
      mx = s;
    }
    float p = __expf(s - mx);
    l += p;
    const float4* vr = (const float4*)(vbuf + t * 40);
#pragma unroll
    for (int k = 0; k < 10; ++k) {
      float4 v4 = vr[k];
      acc[4 * k] += p * v4.x; acc[4 * k + 1] += p * v4.y;
      acc[4 * k + 2] += p * v4.z; acc[4 * k + 3] += p * v4.w;
    }
  }
  // merge across the wave pair via LDS (symmetric)
#pragma unroll
  for (int d = 0; d < 40; ++d) colbuf[d * 256 + tid] = acc[d];
  redm[tid] = mx; redl[tid] = l;
  __syncthreads();                                    // B5
  float lat[40];
  {
    float m2 = redm[ptn];
    float l2 = redl[ptn];
    float nm = fmaxf(mx, m2);
    float a = __expf(mx - nm), b = __expf(m2 - nm);
    float lm = l * a + l2 * b;
    float linv = 1.f / lm;
#pragma unroll
    for (int d = 0; d < 40; ++d)
      lat[d] = (acc[d] * a + colbuf[d * 256 + ptn] * b) * linv;
  }
  __syncthreads();                                    // B6 (colbuf free)

  // ---- lat2 = lat @ ca_out_w^T + ob, split by d-half ----
  float lath[20];
#pragma unroll
  for (int dd = 0; dd < 20; ++dd) lath[dd] = h ? lat[dd + 20] : lat[dd];
  float lp[40];
#pragma unroll
  for (int e = 0; e < 40; ++e) lp[e] = 0.f;
#pragma unroll 1
  for (int dd = 0; dd < 20; ++dd) {
    const float lv = lath[dd];
    const int d = h * 20 + dd;
#pragma unroll
    for (int e = 0; e < 40; ++e) lp[e] += lv * ow[e * 40 + d];
  }
#pragma unroll
  for (int e = 0; e < 40; ++e) colbuf[e * 256 + tid] = lp[e];
  __syncthreads();                                    // B7
  float lat2[40];
#pragma unroll
  for (int e = 0; e < 40; ++e) lat2[e] = ob[e] + lp[e] + colbuf[e * 256 + ptn];
  __syncthreads();                                    // B8 (colbuf free)

  // ---- LN + FFN (e-range split by wave half) ----
  float hh[40];
  {
    float m = 0.f;
#pragma unroll
    for (int d = 0; d < 40; ++d) m += lat2[d];
    m *= (1.f / 40.f);
    float var = 0.f;
#pragma unroll
    for (int d = 0; d < 40; ++d) { float dv = lat2[d] - m; var += dv * dv; }
    float rstd = rsqrtf(var * (1.f / 40.f) + 1e-5f);
#pragma unroll
    for (int d = 0; d < 40; ++d) hh[d] = (lat2[d] - m) * rstd * flw[d] + flb[d];
  }
  float ff[40];
#pragma unroll
  for (int d = 0; d < 40; ++d) ff[d] = 0.f;
#pragma unroll 1
  for (int ee = 0; ee < 80; ++ee) {
    const int e = h * 80 + ee;
    const float* r1 = w1 + e * 40;
    const float* r2 = w1 + (160 + e) * 40;
    float a0 = 0.f, a1 = 0.f;
#pragma unroll
    for (int d = 0; d < 40; ++d) { a0 += hh[d] * r1[d]; a1 += hh[d] * r2[d]; }
    float x1 = a0 + b1[e];
    float g = a1 + b1[160 + e];
    float tv = x1 * (0.5f * g * (1.f + erff(g * 0.70710678118654752f)));
#pragma unroll
    for (int d = 0; d < 40; ++d) ff[d] += tv * w2[d * 160 + e];
  }
#pragma unroll
  for (int d = 0; d < 40; ++d) colbuf[d * 256 + tid] = ff[d];
  __syncthreads();                                    // B9
  float r = outb[0];
#pragma unroll
  for (int d = 0; d < 40; ++d) {
    float f = ff[d] + colbuf[d * 256 + ptn] + b2[d];
    r += (lat2[d] + f) * outw[d];
  }
  if (h == 0) out[n] = r;
}

extern "C" void kernel_launch(void* const* d_in, const int* in_sizes, int n_in,
                              void* d_out, int out_size, void* d_ws, size_t ws_size,
                              hipStream_t stream) {
  const float* mash   = (const float*)d_in[0];
  const float* qry    = (const float*)d_in[1];
  const float* lnw    = (const float*)d_in[2];
  const float* linw   = (const float*)d_in[3];
  const float* lconvw = (const float*)d_in[4];
  const float* lconvb = (const float*)d_in[5];
  const float* lxpw   = (const float*)d_in[6];
  const float* ldtw   = (const float*)d_in[7];
  const float* ldtb   = (const float*)d_in[8];
  const float* lAlog  = (const float*)d_in[9];
  const float* lD     = (const float*)d_in[10];
  const float* loutw  = (const float*)d_in[11];
  const float* pew    = (const float*)d_in[12];
  const float* peb    = (const float*)d_in[13];
  const float* lnqw   = (const float*)d_in[14];
  const float* lnqb   = (const float*)d_in[15];
  const float* lncw   = (const float*)d_in[16];
  const float* lncb   = (const float*)d_in[17];
  const float* qw     = (const float*)d_in[18];
  const float* kvw    = (const float*)d_in[19];
  const float* oww    = (const float*)d_in[20];
  const float* owb    = (const float*)d_in[21];
  const float* flnw   = (const float*)d_in[22];
  const float* flnb   = (const float*)d_in[23];
  const float* w1     = (const float*)d_in[24];
  const float* b1     = (const float*)d_in[25];
  const float* w2     = (const float*)d_in[26];
  const float* b2     = (const float*)d_in[27];
  const float* outw   = (const float*)d_in[28];
  const float* outb   = (const float*)d_in[29];

  // ws layout (f32 elements): xb0[16000] xb1[16000] k[16000] v[16000] flags
  float* wsf = (float*)d_ws;
  float* xb0 = wsf;
  float* xb1 = wsf + 16000;
  float* kbuf = wsf + 32000;
  float* vbuf = wsf + 48000;
  int* flags = (int*)(wsf + 64000);

  hipLaunchKernelGGL(init_flags, dim3(16), dim3(256), 0, stream, flags);
  hipLaunchKernelGGL(mamba_pipe, dim3(128), dim3(TPB1), 0, stream,
                     mash, lnw, linw, lconvw, lconvb, lxpw, ldtw, ldtb, lAlog,
                     lD, loutw, xb0, xb1, flags);
  // WG 127 (odd) writes xb1
  hipLaunchKernelGGL(kv_kernel, dim3(400), dim3(64), 0, stream,
                     xb1, lncw, lncb, kvw, kbuf, vbuf);
  hipLaunchKernelGGL(query_kernel, dim3(512), dim3(256), 0, stream,
                     qry, pew, peb, lnqw, lnqb, qw, oww, owb, flnw, flnb,
                     w1, b1, w2, b2, outw, outb, kbuf, vbuf, (float*)d_out);
}